// Round 13
// baseline (184.427 us; speedup 1.0000x reference)
//
#include <hip/hip_runtime.h>
#include <hip/hip_bf16.h>
#include <stdint.h>

// EncoderBlock: B=8, S=1024, D=512, H=12, HS=42 (padded to 64 for GEMM).
// Only batch 0's attention is used (reference quirk: attn[0] + x).

typedef unsigned short u16;
typedef __attribute__((ext_vector_type(8))) short short8;  // 8 bf16 = 4 VGPRs
typedef __attribute__((ext_vector_type(4))) float f32x4;

__device__ __forceinline__ u16 f2bf(float f) {
  union { float f; unsigned u; } x; x.f = f;
  return (u16)((x.u + 0x7FFFu + ((x.u >> 16) & 1u)) >> 16);  // RNE
}
__device__ __forceinline__ float bf2f(u16 u) {
  union { unsigned u; float f; } x; x.u = ((unsigned)u) << 16;
  return x.f;
}

// async global->LDS, 16B per lane; LDS dest is wave-uniform base + lane*16.
__device__ __forceinline__ void gload_lds16(const u16* g, u16* l) {
  __builtin_amdgcn_global_load_lds(
      (__attribute__((address_space(1))) void*)g,
      (__attribute__((address_space(3))) void*)l, 16, 0, 0);
}

__device__ __forceinline__ float wred_sum(float v) {
#pragma unroll
  for (int off = 32; off > 0; off >>= 1) v += __shfl_xor(v, off, 64);
  return v;
}

// tanh-form GELU: 0.5x(1+tanh(u)) == x / (1 + exp(-2u)), u = c0*x + c1*x^3.
__device__ __forceinline__ float gelu_fast(float t) {
  const float p = __builtin_fmaf(0.0356774081f, t * t, 0.7978845608f);
  return t / (1.0f + __expf(-2.0f * t * p));
}

#define MFMA16x16(a, b, c) __builtin_amdgcn_mfma_f32_16x16x32_bf16(a, b, c, 0, 0, 0)

enum { EP_BF16 = 0, EP_F32B = 2, EP_GELU = 3, EP_ATOM = 7 };

// ---------------------------------------------------------------------------
// GEMM core (r3/r6-proven, measured-best): 128x128 tile, BK=32, 4 waves 2x2,
// dbuf LDS (32KB), one barrier per K-tile, next-tile gload under MFMA.
// r11 lesson: 4 blocks/CU is the register ceiling (5 spills the accumulator).
// r12 lesson: bx-FASTEST XCD decode (r6/r8) beats the "L2-friendly" one —
// latency x concurrency binds, not bytes; high-BW L3 streaming is fine.
// ---------------------------------------------------------------------------
template <int EP>
__device__ __forceinline__ void gemm_core(u16* lds, const u16* __restrict__ Ab,
                                          int lda, const u16* __restrict__ Bb,
                                          int ldb, void* __restrict__ Cv,
                                          int ldc, int K,
                                          const float* __restrict__ bias,
                                          int m0, int n0) {
  u16* lA[2] = {lds, lds + 4096};
  u16* lB[2] = {lds + 8192, lds + 12288};

  const int tid = threadIdx.x;
  const int w = tid >> 6;
  const int l = tid & 63;
  const int wr = w >> 1;
  const int wc = w & 1;
  const int NT = K >> 5;

  f32x4 acc[4][4];
#pragma unroll
  for (int i = 0; i < 4; ++i)
#pragma unroll
    for (int j = 0; j < 4; ++j) acc[i][j] = (f32x4){0.f, 0.f, 0.f, 0.f};

  // staging: wave w covers rows [w*32, w*32+32); lane -> row l>>2, gran l&3.
  const int srow = w * 32 + (l >> 2);
  const int sk = (l & 3) * 8;
  const u16* gA = Ab + (long)(m0 + srow) * lda + sk;
  const u16* gB = Bb + (long)(n0 + srow) * ldb + sk;
  const int dOff = w * 1024;

  // fragment reads: row = l&15, k-granule = l>>4
  const int aoff = (wr * 64 + (l & 15)) * 32 + (l >> 4) * 8;
  const int boff = (wc * 64 + (l & 15)) * 32 + (l >> 4) * 8;

  auto stage = [&](int b_, int t_) {
    const int k0 = t_ * 32;
    gload_lds16(gA + k0, lA[b_] + dOff);
    gload_lds16(gA + k0 + 16 * lda, lA[b_] + dOff + 512);
    gload_lds16(gB + k0, lB[b_] + dOff);
    gload_lds16(gB + k0 + 16 * ldb, lB[b_] + dOff + 512);
  };

  stage(0, 0);
  __syncthreads();

  int buf = 0;
  for (int t = 0; t < NT; ++t) {
    short8 af[4], bfv[4];
#pragma unroll
    for (int mi = 0; mi < 4; ++mi)
      af[mi] = *(const short8*)&lA[buf][aoff + mi * 16 * 32];
#pragma unroll
    for (int ni = 0; ni < 4; ++ni)
      bfv[ni] = *(const short8*)&lB[buf][boff + ni * 16 * 32];
    if (t + 1 < NT) stage(buf ^ 1, t + 1);
#pragma unroll
    for (int mi = 0; mi < 4; ++mi)
#pragma unroll
      for (int ni = 0; ni < 4; ++ni)
        acc[mi][ni] = MFMA16x16(af[mi], bfv[ni], acc[mi][ni]);
    __syncthreads();
    buf ^= 1;
  }

  // C/D mapping: col = lane&15, row = (lane>>4)*4 + reg  [m89-verified]
  const int rbase = m0 + wr * 64 + (l >> 4) * 4;
  const int cbase = n0 + wc * 64 + (l & 15);
#pragma unroll
  for (int mi = 0; mi < 4; ++mi) {
#pragma unroll
    for (int ni = 0; ni < 4; ++ni) {
#pragma unroll
      for (int j = 0; j < 4; ++j) {
        const int row = rbase + mi * 16 + j;
        const int col = cbase + ni * 16;
        const float v = acc[mi][ni][j];
        if (EP == EP_BF16) {
          ((u16*)Cv)[(long)row * ldc + col] = f2bf(v);
        } else if (EP == EP_F32B) {
          ((float*)Cv)[(long)row * ldc + col] = v + bias[col];
        } else if (EP == EP_GELU) {
          ((u16*)Cv)[(long)row * ldc + col] = f2bf(gelu_fast(v + bias[col]));
        } else {  // EP_ATOM: accumulate into pre-filled output
          atomicAdd(&((float*)Cv)[(long)row * ldc + col], v);
        }
      }
    }
  }
}

// XCD swizzle, r6/r8-measured-best decode: bx FASTEST within each XCD chunk.
template <int EP>
__launch_bounds__(256, 4)
__global__ void gemm_k(const u16* __restrict__ A, int lda, long sAz,
                       const u16* __restrict__ Bt, int ldb, long sBz,
                       void* __restrict__ Cv, int ldc, int K,
                       const float* __restrict__ bias) {
  __shared__ u16 lds[4 * 128 * 32];
  const int gx = gridDim.x, gy = gridDim.y, gz = gridDim.z;
  const int lin = blockIdx.x + gx * (blockIdx.y + gy * blockIdx.z);
  const int nwg = gx * gy * gz;
  const int wg = (lin & 7) * (nwg >> 3) + (lin >> 3);
  const int bx = wg % gx;
  const int tmp = wg / gx;
  const int by = tmp % gy;
  const int z = tmp / gy;
  const u16* Ab = A + (long)z * sAz;  // for EP_ATOM: sAz/sBz = k-offset
  const u16* Bb = Bt + (long)z * sBz;
  gemm_core<EP>(lds, Ab, lda, Bb, ldb, Cv, ldc, K, bias, bx * 128, by * 128);
}

// merged q/k + v^T projections: 192 blocks.
__launch_bounds__(256, 4)
__global__ void qkvt_kernel(const u16* __restrict__ n1,
                            const u16* __restrict__ BtQKV,
                            u16* __restrict__ qkvc,
                            const u16* __restrict__ wvT,
                            u16* __restrict__ vt) {
  __shared__ u16 lds[4 * 128 * 32];
  const int lin = blockIdx.x;  // 192
  const int wg = (lin & 7) * 24 + (lin >> 3);
  if (wg < 96) {
    gemm_core<EP_BF16>(lds, n1, 512, BtQKV, 512, qkvc, 1536, 512, nullptr,
                       (wg & 7) * 128, (wg >> 3) * 128);
  } else {
    const int v = wg - 96;
    gemm_core<EP_BF16>(lds, wvT, 512, n1, 512, vt, 1024, 512, nullptr,
                       (v % 12) * 128, (v / 12) * 128);
  }
}

// ---------------------------------------------------------------------------
// flash attention (r8-proven): one block per (head, 64-row q-tile).
// ---------------------------------------------------------------------------
__device__ __forceinline__ short8 frag_read(const u16* base, int row, int ks,
                                            int l) {
  const int g = (ks * 4 + (l >> 4)) ^ (l & 7);
  return *(const short8*)&base[row * 64 + g * 8];
}

__launch_bounds__(256, 2)
__global__ void flash_attn(const u16* __restrict__ qkvc,
                           const u16* __restrict__ vt,
                           u16* __restrict__ cat) {
  __shared__ u16 lQ[64 * 64];      // 8KB
  __shared__ u16 lK[2][64 * 64];   // 16KB
  __shared__ u16 lV[2][64 * 64];   // 16KB (rows = e, cols = kv; from vt)
  __shared__ u16 lP[4][16 * 64];   // 8KB, per-wave private
  const int h = blockIdx.x;
  const int q0 = blockIdx.y * 64;
  const int tid = threadIdx.x;
  const int w = tid >> 6;
  const int l = tid & 63;
  const int sg = ((l & 7) ^ (l >> 3)) * 8;  // inverse-swizzled source granule
  const int sr = w * 8 + (l >> 3);          // stage row within 32-row chunk

#define FA_STAGE(t_, b_)                                                    \
  do {                                                                      \
    const int kv_ = (t_) * 64;                                              \
    gload_lds16(qkvc + (long)(kv_ + sr) * 1536 + 768 + h * 64 + sg,         \
                lK[b_] + w * 8 * 64);                                       \
    gload_lds16(qkvc + (long)(kv_ + 32 + sr) * 1536 + 768 + h * 64 + sg,    \
                lK[b_] + (32 + w * 8) * 64);                                \
    gload_lds16(vt + (long)(h * 128 + sr) * 1024 + kv_ + sg,                \
                lV[b_] + w * 8 * 64);                                       \
    gload_lds16(vt + (long)(h * 128 + 32 + sr) * 1024 + kv_ + sg,           \
                lV[b_] + (32 + w * 8) * 64);                                \
  } while (0)

  gload_lds16(qkvc + (long)(q0 + sr) * 1536 + h * 64 + sg, lQ + w * 8 * 64);
  gload_lds16(qkvc + (long)(q0 + 32 + sr) * 1536 + h * 64 + sg,
              lQ + (32 + w * 8) * 64);
  FA_STAGE(0, 0);
  __syncthreads();

  const short8 qf0 = frag_read(lQ, w * 16 + (l & 15), 0, l);
  const short8 qf1 = frag_read(lQ, w * 16 + (l & 15), 1, l);

  f32x4 accO[4];
  float m_run[4], l_run[4];
#pragma unroll
  for (int i = 0; i < 4; ++i) {
    accO[i] = (f32x4){0.f, 0.f, 0.f, 0.f};
    m_run[i] = -3.0e38f;
    l_run[i] = 0.f;
  }

  int buf = 0;
  for (int t = 0; t < 16; ++t) {
    if (t + 1 < 16) FA_STAGE(t + 1, buf ^ 1);
    f32x4 s[4];
#pragma unroll
    for (int ni = 0; ni < 4; ++ni) {
      const short8 kf0 = frag_read(lK[buf], ni * 16 + (l & 15), 0, l);
      const short8 kf1 = frag_read(lK[buf], ni * 16 + (l & 15), 1, l);
      s[ni] = MFMA16x16(qf0, kf0, ((f32x4){0.f, 0.f, 0.f, 0.f}));
      s[ni] = MFMA16x16(qf1, kf1, s[ni]);
    }
#pragma unroll
    for (int j = 0; j < 4; ++j) {
      float mx = fmaxf(fmaxf(s[0][j], s[1][j]), fmaxf(s[2][j], s[3][j]));
      mx = fmaxf(mx, __shfl_xor(mx, 1));
      mx = fmaxf(mx, __shfl_xor(mx, 2));
      mx = fmaxf(mx, __shfl_xor(mx, 4));
      mx = fmaxf(mx, __shfl_xor(mx, 8));
      const float mn = fmaxf(m_run[j], mx);
      const float corr = __expf(m_run[j] - mn);
      m_run[j] = mn;
      float ps = 0.f;
#pragma unroll
      for (int ni = 0; ni < 4; ++ni) {
        const float p = __expf(s[ni][j] - mn);
        s[ni][j] = p;
        ps += p;
      }
      ps += __shfl_xor(ps, 1);
      ps += __shfl_xor(ps, 2);
      ps += __shfl_xor(ps, 4);
      ps += __shfl_xor(ps, 8);
      l_run[j] = l_run[j] * corr + ps;
#pragma unroll
      for (int ne = 0; ne < 4; ++ne) accO[ne][j] *= corr;
    }
#pragma unroll
    for (int ni = 0; ni < 4; ++ni) {
#pragma unroll
      for (int j = 0; j < 4; ++j) {
        const int row = (l >> 4) * 4 + j;
        const int col = ni * 16 + (l & 15);
        const int boff = row * 128 + (((col >> 3) ^ (row & 7)) << 4) +
                         (col & 7) * 2;
        *(u16*)((char*)lP[w] + boff) = f2bf(s[ni][j]);
      }
    }
    asm volatile("s_waitcnt lgkmcnt(0)" ::: "memory");
    __builtin_amdgcn_sched_barrier(0);
    const short8 pf0 = frag_read(lP[w], (l & 15), 0, l);
    const short8 pf1 = frag_read(lP[w], (l & 15), 1, l);
#pragma unroll
    for (int ne = 0; ne < 4; ++ne) {
      const short8 vf0 = frag_read(lV[buf], ne * 16 + (l & 15), 0, l);
      const short8 vf1 = frag_read(lV[buf], ne * 16 + (l & 15), 1, l);
      accO[ne] = MFMA16x16(pf0, vf0, accO[ne]);
      accO[ne] = MFMA16x16(pf1, vf1, accO[ne]);
    }
    __syncthreads();
    buf ^= 1;
  }
#undef FA_STAGE

#pragma unroll
  for (int j = 0; j < 4; ++j) {
    const float inv = 1.0f / l_run[j];
    const int row = q0 + w * 16 + (l >> 4) * 4 + j;
#pragma unroll
    for (int ne = 0; ne < 4; ++ne) {
      const int e = ne * 16 + (l & 15);
      if (e < 42)
        cat[(long)row * 512 + h * 42 + e] = f2bf(accO[ne][j] * inv);
    }
  }
}

// ---------------------------------------------------------------------------
// fused prep (coalesced): weight re-layouts + zero(cat pad cols) + LN1.
// ---------------------------------------------------------------------------
__device__ __forceinline__ void transpose_body(const float* __restrict__ in,
                                               u16* __restrict__ out, int N,
                                               int Kin, int Kpad, int blk,
                                               int gx, int t, float* smem) {
  const int n0 = (blk % gx) * 64;
  const int k0 = (blk / gx) * 64;
  const int tc = t & 63;
  const int tr = t >> 6;  // 0..3
#pragma unroll
  for (int r = 0; r < 16; ++r) {
    const int kr = tr * 16 + r;
    const int kg = k0 + kr;
    smem[kr * 65 + tc] = (kg < Kin) ? in[(long)kg * N + n0 + tc] : 0.f;
  }
  __syncthreads();
  const int nr0 = t >> 4;       // 0..15
  const int kc = (t & 15) * 4;  // 16 lanes x 8B = 128B contiguous per row
#pragma unroll
  for (int p = 0; p < 4; ++p) {
    const int nr = nr0 + p * 16;
    ushort4 v;
    v.x = f2bf(smem[(kc + 0) * 65 + nr]);
    v.y = f2bf(smem[(kc + 1) * 65 + nr]);
    v.z = f2bf(smem[(kc + 2) * 65 + nr]);
    v.w = f2bf(smem[(kc + 3) * 65 + nr]);
    *(ushort4*)&out[(long)(n0 + nr) * Kpad + k0 + kc] = v;
  }
}

__global__ void prep_fused(const float* __restrict__ wq,
                           const float* __restrict__ wk,
                           const float* __restrict__ wv,
                           const float* __restrict__ w_proj,
                           const float* __restrict__ w1,
                           const float* __restrict__ w2,
                           const float* __restrict__ x,
                           const float* __restrict__ gamma,
                           const float* __restrict__ beta,
                           u16* __restrict__ BtQKV, u16* __restrict__ wvT,
                           u16* __restrict__ BtP, u16* __restrict__ Bt1,
                           u16* __restrict__ Bt2, u16* __restrict__ cat,
                           u16* __restrict__ n1, float scale) {
  __shared__ float smem[64 * 65];
  const int blk = blockIdx.x;
  const int t = threadIdx.x;
  if (blk < 192) {
    // BtQKV[pq*768 + h*64 + e][d] = w[(h*512+d)*42+e] (q pre-scaled, e>=42->0)
    const int pq = blk / 96;
    const int rem = blk % 96;
    const int h = rem >> 3;
    const int d0 = (rem & 7) * 64;
    const float* src = (pq ? wk : wq) + ((long)h * 512 + d0) * 42;
    for (int i = t; i < 2688; i += 256) smem[(i / 42) * 43 + (i % 42)] = src[i];
    __syncthreads();
    const float sc = pq ? 1.0f : scale;
    const int d = t & 63;
#pragma unroll
    for (int p = 0; p < 16; ++p) {
      const int e = (t >> 6) + p * 4;
      const float v = (e < 42) ? smem[d * 43 + e] * sc : 0.f;
      BtQKV[((long)(pq * 768 + h * 64 + e)) * 512 + d0 + d] = f2bf(v);
    }
  } else if (blk < 288) {
    // wvT[h*128 + e][d] = wv[(h*512+d)*42+e] (e>=42 -> 0)
    const int b = blk - 192;
    const int h = b >> 3;
    const int d0 = (b & 7) * 64;
    const float* src = wv + ((long)h * 512 + d0) * 42;
    for (int i = t; i < 2688; i += 256) smem[(i / 42) * 43 + (i % 42)] = src[i];
    __syncthreads();
    const int d = t & 63;
#pragma unroll
    for (int p = 0; p < 32; ++p) {
      const int e = (t >> 6) + p * 4;
      const float v = (e < 42) ? smem[d * 43 + e] : 0.f;
      wvT[((long)(h * 128 + e)) * 512 + d0 + d] = f2bf(v);
    }
  } else if (blk < 352) {  // BtP = w_proj^T (pad 504->512)
    transpose_body(w_proj, BtP, 512, 504, 512, blk - 288, 8, t, smem);
  } else if (blk < 608) {  // Bt1 = w1^T
    transpose_body(w1, Bt1, 2048, 512, 512, blk - 352, 32, t, smem);
  } else if (blk < 864) {  // Bt2 = w2^T
    transpose_body(w2, Bt2, 512, 2048, 2048, blk - 608, 8, t, smem);
  } else if (blk < 896) {  // zero cat pad cols 504..511 (rest overwritten)
    const int i = (blk - 864) * 256 + t;  // < 8192
    cat[(long)(i >> 3) * 512 + 504 + (i & 7)] = 0;
  } else {  // ln1 over x[0]
    const int s = blk - 896;
    const float* row = x + (long)s * 512;
    const float v0 = row[t];
    const float v1 = row[t + 256];
    float sum = wred_sum(v0 + v1);
    float sq = wred_sum(v0 * v0 + v1 * v1);
    if ((t & 63) == 0) { smem[t >> 6] = sum; smem[8 + (t >> 6)] = sq; }
    __syncthreads();
    sum = smem[0] + smem[1] + smem[2] + smem[3];
    sq = smem[8] + smem[9] + smem[10] + smem[11];
    const float mu = sum * (1.0f / 512.0f);
    const float rstd = rsqrtf(sq * (1.0f / 512.0f) - mu * mu + 1e-5f);
    n1[(long)s * 512 + t] = f2bf((v0 - mu) * rstd * gamma[t] + beta[t]);
    n1[(long)s * 512 + t + 256] =
        f2bf((v1 - mu) * rstd * gamma[t + 256] + beta[t + 256]);
  }
}

// ln2: v = x + aproj (bcast); n2 = LN(v); outp = v + b2 (pre-fill for MLP2's
// atomic epilogue).
__global__ void ln2_kernel(const float* __restrict__ x,
                           const float* __restrict__ aproj,
                           const float* __restrict__ gamma,
                           const float* __restrict__ beta,
                           const float* __restrict__ b2,
                           u16* __restrict__ n2, float* __restrict__ outp) {
  __shared__ float red[16];
  const int r = blockIdx.x;  // b*1024 + s
  const int t = threadIdx.x;
  const int s = r & 1023;
  const float* xr = x + (long)r * 512;
  const float* ar = aproj + (long)s * 512;
  const float v0 = xr[t] + ar[t];
  const float v1 = xr[t + 256] + ar[t + 256];
  outp[(long)r * 512 + t] = v0 + b2[t];
  outp[(long)r * 512 + t + 256] = v1 + b2[t + 256];
  float sum = wred_sum(v0 + v1);
  float sq = wred_sum(v0 * v0 + v1 * v1);
  if ((t & 63) == 0) { red[t >> 6] = sum; red[8 + (t >> 6)] = sq; }
  __syncthreads();
  sum = red[0] + red[1] + red[2] + red[3];
  sq = red[8] + red[9] + red[10] + red[11];
  const float mu = sum * (1.0f / 512.0f);
  const float rstd = rsqrtf(sq * (1.0f / 512.0f) - mu * mu + 1e-5f);
  n2[(long)r * 512 + t] = f2bf((v0 - mu) * rstd * gamma[t] + beta[t]);
  n2[(long)r * 512 + t + 256] =
      f2bf((v1 - mu) * rstd * gamma[t + 256] + beta[t + 256]);
}

// ---------------------------------------------------------------------------
extern "C" void kernel_launch(void* const* d_in, const int* in_sizes, int n_in,
                              void* d_out, int out_size, void* d_ws,
                              size_t ws_size, hipStream_t stream) {
  const float* x = (const float*)d_in[0];
  const float* wk = (const float*)d_in[1];   // wk before wq in dict order
  const float* wq = (const float*)d_in[2];
  const float* wv = (const float*)d_in[3];
  const float* w_proj = (const float*)d_in[4];
  const float* b_proj = (const float*)d_in[5];
  const float* gamma = (const float*)d_in[6];
  const float* beta = (const float*)d_in[7];
  const float* w1 = (const float*)d_in[8];
  const float* b1 = (const float*)d_in[9];
  const float* w2 = (const float*)d_in[10];
  const float* b2 = (const float*)d_in[11];

  char* base = (char*)d_ws;
  size_t off = 0;
  auto alloc = [&](size_t bytes) -> void* {
    void* p = base + off;
    off += (bytes + 255) & ~(size_t)255;
    return p;
  };
  u16* n1 = (u16*)alloc(1024L * 512 * 2);        // LN1(x[0]) bf16
  u16* qkvc = (u16*)alloc(1024L * 1536 * 2);     // [s][(q|k) h e64] bf16
  u16* wvT = (u16*)alloc(1536L * 512 * 2);       // [h*128+e][d]
  u16* vt = (u16*)alloc(1536L * 1024 * 2);       // v^T [h*128+e][t]
  u16* cat = (u16*)alloc(1024L * 512 * 2);       // concat heads, pad->512
  float* aproj = (float*)alloc(1024L * 512 * 4); // attn @ w_proj + b_proj
  u16* n2 = (u16*)alloc(8192L * 512 * 2);        // LN2 bf16
  u16* hbuf = (u16*)alloc(8192L * 2048 * 2);     // gelu(mlp1) bf16
  u16* BtQKV = (u16*)alloc(1536L * 512 * 2);
  u16* BtP = (u16*)alloc(512L * 512 * 2);
  u16* Bt1 = (u16*)alloc(2048L * 512 * 2);
  u16* Bt2 = (u16*)alloc(512L * 2048 * 2);
  (void)ws_size; (void)in_sizes; (void)n_in; (void)out_size;

  const float scale = 0.15430334996209191f;  // 42^-0.5 folded into q weights

  // all prep + LN1 in one launch (1920 blocks, coalesced re-layouts)
  prep_fused<<<1920, 256, 0, stream>>>(wq, wk, wv, w_proj, w1, w2, x, gamma,
                                       beta, BtQKV, wvT, BtP, Bt1, Bt2, cat,
                                       n1, scale);
  // merged q,k and v^T projections (192 blocks, one launch)
  qkvt_kernel<<<192, 256, 0, stream>>>(n1, BtQKV, qkvc, wvT, vt);
  // fused attention: scores+softmax+PV+scatter
  flash_attn<<<dim3(12, 16), 256, 0, stream>>>(qkvc, vt, cat);
  // attn_proj = concat @ w_proj + b_proj: [1024,512] f32 (nwg=32)
  gemm_k<EP_F32B><<<dim3(8, 4, 1), 256, 0, stream>>>(
      cat, 512, 0, BtP, 512, 0, aproj, 512, 512, b_proj);
  // ln2 pre-fills d_out = (x+aproj) + b2 for the atomic MLP2 epilogue
  ln2_kernel<<<8192, 256, 0, stream>>>(x, aproj, gamma, beta, b2, n2,
                                       (float*)d_out);
  // h = gelu(n2 @ w1 + b1): [8192,2048] bf16 (nwg=1024, 4 blocks/CU)
  gemm_k<EP_GELU><<<dim3(64, 16, 1), 256, 0, stream>>>(
      n2, 512, 0, Bt1, 512, 0, hbuf, 2048, 512, b1);
  // MLP2 split-K=4 (K=512/slice, nwg=1024 -> 4 blocks/CU): atomicAdd
  gemm_k<EP_ATOM><<<dim3(64, 4, 4), 256, 0, stream>>>(
      hbuf, 2048, 512, Bt2, 2048, 512, d_out, 512, 512, nullptr);
}

// Round 14
// 158.096 us; speedup vs baseline: 1.1666x; 1.1666x over previous
//
#include <hip/hip_runtime.h>
#include <hip/hip_bf16.h>
#include <stdint.h>

// EncoderBlock: B=8, S=1024, D=512, H=12, HS=42 (padded to 64 for GEMM).
// Only batch 0's attention is used (reference quirk: attn[0] + x).

typedef unsigned short u16;
typedef __attribute__((ext_vector_type(8))) short short8;  // 8 bf16 = 4 VGPRs
typedef __attribute__((ext_vector_type(4))) float f32x4;

__device__ __forceinline__ u16 f2bf(float f) {
  union { float f; unsigned u; } x; x.f = f;
  return (u16)((x.u + 0x7FFFu + ((x.u >> 16) & 1u)) >> 16);  // RNE
}
__device__ __forceinline__ float bf2f(u16 u) {
  union { unsigned u; float f; } x; x.u = ((unsigned)u) << 16;
  return x.f;
}

// async global->LDS, 16B per lane; LDS dest is wave-uniform base + lane*16.
__device__ __forceinline__ void gload_lds16(const u16* g, u16* l) {
  __builtin_amdgcn_global_load_lds(
      (__attribute__((address_space(1))) void*)g,
      (__attribute__((address_space(3))) void*)l, 16, 0, 0);
}

__device__ __forceinline__ float wred_sum(float v) {
#pragma unroll
  for (int off = 32; off > 0; off >>= 1) v += __shfl_xor(v, off, 64);
  return v;
}

// tanh-form GELU: 0.5x(1+tanh(u)) == x / (1 + exp(-2u)), u = c0*x + c1*x^3.
__device__ __forceinline__ float gelu_fast(float t) {
  const float p = __builtin_fmaf(0.0356774081f, t * t, 0.7978845608f);
  return t / (1.0f + __expf(-2.0f * t * p));
}

#define MFMA16x16(a, b, c) __builtin_amdgcn_mfma_f32_16x16x32_bf16(a, b, c, 0, 0, 0)

enum { EP_BF16 = 0, EP_F32B = 2, EP_GELU = 3, EP_ATOM = 7 };

// ---------------------------------------------------------------------------
// gemm8: 256x256 tile, BK=64, 512 thr = 8 waves (2M x 4N), per-wave C 128x64.
// Per K-tile: 4 quadrant-phases {12 ds_read; sched_barrier; setprio(1);
// 16 MFMA; setprio(0); s_barrier}. Next tile's 8 global_load_lds issued at
// tile TOP and kept in flight across all intra-tile barriers (raw s_barrier
// does NOT drain vmcnt); drained only at tile boundary (vmcnt(0)+barrier),
// ~4 phases after issue -> HBM latency covered. LDS 128KB (2 x [A 256x64 |
// B 256x64]), XOR-swizzled granules (flash_attn-proven scheme: pre-swizzled
// global source col, read granule g^(row&7)).
// Race audit: (1) reads of buf p (tile s) preceded by vmcnt(0)+barrier at
// end of tile s-1 -> all waves' stages complete & visible. (2) stages into
// buf p^1 at tile-s top: buf p^1 last read in tile s-1; every wave's
// ds_reads completed before its phase-3 MFMA (compiler lgkmcnt) which
// precedes the end-of-tile barriers -> no clobber. (3) barriers uniform.
// ---------------------------------------------------------------------------
template <int EP>
__launch_bounds__(512, 1)
__global__ void gemm8(const u16* __restrict__ A, int lda,
                      const u16* __restrict__ Bt, int ldb,
                      void* __restrict__ Cv, int ldc, int K,
                      const float* __restrict__ bias) {
  __shared__ u16 lds[65536];  // 128 KB: [p][A 16384 | B 16384]
  const int lin = blockIdx.x + gridDim.x * blockIdx.y;
  const int nwg = gridDim.x * gridDim.y;
  const int wg = (lin & 7) * (nwg >> 3) + (lin >> 3);
  const int bx = wg % gridDim.x;
  const int by = wg / gridDim.x;
  const int m0 = bx * 256, n0 = by * 256;
  const int tid = threadIdx.x;
  const int w = tid >> 6, l = tid & 63;
  const int wm = w >> 2, wn = w & 3;
  const int la = l & 15, lg = l >> 4, l7 = l & 7;
  const int NS = K >> 6;

  f32x4 acc[8][4];
#pragma unroll
  for (int i = 0; i < 8; ++i)
#pragma unroll
    for (int j = 0; j < 4; ++j) acc[i][j] = (f32x4){0.f, 0.f, 0.f, 0.f};

  // staging: one gload instr = 64 rows x 64 cols (512 thr x 16B); 4 per
  // matrix. Linear LDS dest (row = w*8 + l>>3, granule = l&7); source col
  // granule pre-swizzled by row&7 (= l>>3).
  const int srl = (w << 3) + (l >> 3);            // row in 64-row group
  const int sgc = ((l & 7) ^ (l >> 3)) << 3;      // source col (elems)
  auto stage = [&](int p, int t) {
    const long kof = (long)t * 64 + sgc;
#pragma unroll
    for (int i = 0; i < 4; ++i)
      gload_lds16(A + (long)(m0 + i * 64 + srl) * lda + kof,
                  lds + p * 32768 + i * 4096 + (w << 9));
#pragma unroll
    for (int i = 0; i < 4; ++i)
      gload_lds16(Bt + (long)(n0 + i * 64 + srl) * ldb + kof,
                  lds + p * 32768 + 16384 + i * 4096 + (w << 9));
  };

  stage(0, 0);
  asm volatile("s_waitcnt vmcnt(0)" ::: "memory");
  __builtin_amdgcn_sched_barrier(0);
  __builtin_amdgcn_s_barrier();

  for (int s = 0; s < NS; ++s) {
    const int p = s & 1;
    if (s + 1 < NS) stage(p ^ 1, s + 1);  // in flight across this tile
#pragma unroll
    for (int q = 0; q < 4; ++q) {  // quadrant (mh, nh) of per-wave 128x64
      const int mh = q >> 1, nh = q & 1;
      short8 af[4][2], bf[2][2];
#pragma unroll
      for (int mi = 0; mi < 4; ++mi) {
        const int row = wm * 128 + mh * 64 + mi * 16 + la;
#pragma unroll
        for (int ks = 0; ks < 2; ++ks) {
          const int pg = ((ks << 2) + lg) ^ l7;
          af[mi][ks] = *(const short8*)&lds[p * 32768 + row * 64 + pg * 8];
        }
      }
#pragma unroll
      for (int ni = 0; ni < 2; ++ni) {
        const int row = wn * 64 + nh * 32 + ni * 16 + la;
#pragma unroll
        for (int ks = 0; ks < 2; ++ks) {
          const int pg = ((ks << 2) + lg) ^ l7;
          bf[ni][ks] =
              *(const short8*)&lds[p * 32768 + 16384 + row * 64 + pg * 8];
        }
      }
      __builtin_amdgcn_sched_barrier(0);
      __builtin_amdgcn_s_setprio(1);
#pragma unroll
      for (int mi = 0; mi < 4; ++mi)
#pragma unroll
        for (int ni = 0; ni < 2; ++ni)
#pragma unroll
          for (int ks = 0; ks < 2; ++ks)
            acc[mh * 4 + mi][nh * 2 + ni] = MFMA16x16(
                af[mi][ks], bf[ni][ks], acc[mh * 4 + mi][nh * 2 + ni]);
      __builtin_amdgcn_s_setprio(0);
      __builtin_amdgcn_s_barrier();
    }
    if (s + 1 < NS) {
      asm volatile("s_waitcnt vmcnt(0)" ::: "memory");
      __builtin_amdgcn_sched_barrier(0);
      __builtin_amdgcn_s_barrier();
    }
  }

  // epilogue: C/D mapping col=lane&15, row=(lane>>4)*4+reg
#pragma unroll
  for (int mh = 0; mh < 2; ++mh)
#pragma unroll
    for (int mi = 0; mi < 4; ++mi)
#pragma unroll
      for (int nh = 0; nh < 2; ++nh)
#pragma unroll
        for (int ni = 0; ni < 2; ++ni)
#pragma unroll
          for (int j = 0; j < 4; ++j) {
            const int row = m0 + wm * 128 + mh * 64 + mi * 16 + lg * 4 + j;
            const int col = n0 + wn * 64 + nh * 32 + ni * 16 + la;
            const float v = acc[mh * 4 + mi][nh * 2 + ni][j];
            if (EP == EP_GELU) {
              ((u16*)Cv)[(long)row * ldc + col] =
                  f2bf(gelu_fast(v + bias[col]));
            } else if (EP == EP_BF16) {
              ((u16*)Cv)[(long)row * ldc + col] = f2bf(v);
            } else {  // EP_ATOM
              atomicAdd(&((float*)Cv)[(long)row * ldc + col], v);
            }
          }
}

// ---------------------------------------------------------------------------
// GEMM core (r3/r6-proven): 128x128 tile, BK=32, 4 waves 2x2, dbuf LDS,
// one barrier per K-tile. 4 blocks/CU is the register ceiling (r11).
// ---------------------------------------------------------------------------
template <int EP>
__device__ __forceinline__ void gemm_core(u16* lds, const u16* __restrict__ Ab,
                                          int lda, const u16* __restrict__ Bb,
                                          int ldb, void* __restrict__ Cv,
                                          int ldc, int K,
                                          const float* __restrict__ bias,
                                          int m0, int n0) {
  u16* lA[2] = {lds, lds + 4096};
  u16* lB[2] = {lds + 8192, lds + 12288};

  const int tid = threadIdx.x;
  const int w = tid >> 6;
  const int l = tid & 63;
  const int wr = w >> 1;
  const int wc = w & 1;
  const int NT = K >> 5;

  f32x4 acc[4][4];
#pragma unroll
  for (int i = 0; i < 4; ++i)
#pragma unroll
    for (int j = 0; j < 4; ++j) acc[i][j] = (f32x4){0.f, 0.f, 0.f, 0.f};

  const int srow = w * 32 + (l >> 2);
  const int sk = (l & 3) * 8;
  const u16* gA = Ab + (long)(m0 + srow) * lda + sk;
  const u16* gB = Bb + (long)(n0 + srow) * ldb + sk;
  const int dOff = w * 1024;

  const int aoff = (wr * 64 + (l & 15)) * 32 + (l >> 4) * 8;
  const int boff = (wc * 64 + (l & 15)) * 32 + (l >> 4) * 8;

  auto stage = [&](int b_, int t_) {
    const int k0 = t_ * 32;
    gload_lds16(gA + k0, lA[b_] + dOff);
    gload_lds16(gA + k0 + 16 * lda, lA[b_] + dOff + 512);
    gload_lds16(gB + k0, lB[b_] + dOff);
    gload_lds16(gB + k0 + 16 * ldb, lB[b_] + dOff + 512);
  };

  stage(0, 0);
  __syncthreads();

  int buf = 0;
  for (int t = 0; t < NT; ++t) {
    short8 af[4], bfv[4];
#pragma unroll
    for (int mi = 0; mi < 4; ++mi)
      af[mi] = *(const short8*)&lA[buf][aoff + mi * 16 * 32];
#pragma unroll
    for (int ni = 0; ni < 4; ++ni)
      bfv[ni] = *(const short8*)&lB[buf][boff + ni * 16 * 32];
    if (t + 1 < NT) stage(buf ^ 1, t + 1);
#pragma unroll
    for (int mi = 0; mi < 4; ++mi)
#pragma unroll
      for (int ni = 0; ni < 4; ++ni)
        acc[mi][ni] = MFMA16x16(af[mi], bfv[ni], acc[mi][ni]);
    __syncthreads();
    buf ^= 1;
  }

  const int rbase = m0 + wr * 64 + (l >> 4) * 4;
  const int cbase = n0 + wc * 64 + (l & 15);
#pragma unroll
  for (int mi = 0; mi < 4; ++mi) {
#pragma unroll
    for (int ni = 0; ni < 4; ++ni) {
#pragma unroll
      for (int j = 0; j < 4; ++j) {
        const int row = rbase + mi * 16 + j;
        const int col = cbase + ni * 16;
        const float v = acc[mi][ni][j];
        if (EP == EP_BF16) {
          ((u16*)Cv)[(long)row * ldc + col] = f2bf(v);
        } else if (EP == EP_F32B) {
          ((float*)Cv)[(long)row * ldc + col] = v + bias[col];
        } else if (EP == EP_GELU) {
          ((u16*)Cv)[(long)row * ldc + col] = f2bf(gelu_fast(v + bias[col]));
        } else {  // EP_ATOM
          atomicAdd(&((float*)Cv)[(long)row * ldc + col], v);
        }
      }
    }
  }
}

template <int EP>
__launch_bounds__(256, 4)
__global__ void gemm_k(const u16* __restrict__ A, int lda, long sAz,
                       const u16* __restrict__ Bt, int ldb, long sBz,
                       void* __restrict__ Cv, int ldc, int K,
                       const float* __restrict__ bias) {
  __shared__ u16 lds[4 * 128 * 32];
  const int gx = gridDim.x, gy = gridDim.y, gz = gridDim.z;
  const int lin = blockIdx.x + gx * (blockIdx.y + gy * blockIdx.z);
  const int nwg = gx * gy * gz;
  const int wg = (lin & 7) * (nwg >> 3) + (lin >> 3);
  const int bx = wg % gx;
  const int tmp = wg / gx;
  const int by = tmp % gy;
  const int z = tmp / gy;
  const u16* Ab = A + (long)z * sAz;  // for EP_ATOM: sAz/sBz = k-offset
  const u16* Bb = Bt + (long)z * sBz;
  gemm_core<EP>(lds, Ab, lda, Bb, ldb, Cv, ldc, K, bias, bx * 128, by * 128);
}

__launch_bounds__(256, 4)
__global__ void qkvt_kernel(const u16* __restrict__ n1,
                            const u16* __restrict__ BtQKV,
                            u16* __restrict__ qkvc,
                            const u16* __restrict__ wvT,
                            u16* __restrict__ vt) {
  __shared__ u16 lds[4 * 128 * 32];
  const int lin = blockIdx.x;  // 192
  const int wg = (lin & 7) * 24 + (lin >> 3);
  if (wg < 96) {
    gemm_core<EP_BF16>(lds, n1, 512, BtQKV, 512, qkvc, 1536, 512, nullptr,
                       (wg & 7) * 128, (wg >> 3) * 128);
  } else {
    const int v = wg - 96;
    gemm_core<EP_BF16>(lds, wvT, 512, n1, 512, vt, 1024, 512, nullptr,
                       (v % 12) * 128, (v / 12) * 128);
  }
}

// ---------------------------------------------------------------------------
// flash attention (r8-proven): one block per (head, 64-row q-tile).
// ---------------------------------------------------------------------------
__device__ __forceinline__ short8 frag_read(const u16* base, int row, int ks,
                                            int l) {
  const int g = (ks * 4 + (l >> 4)) ^ (l & 7);
  return *(const short8*)&base[row * 64 + g * 8];
}

__launch_bounds__(256, 2)
__global__ void flash_attn(const u16* __restrict__ qkvc,
                           const u16* __restrict__ vt,
                           u16* __restrict__ cat) {
  __shared__ u16 lQ[64 * 64];
  __shared__ u16 lK[2][64 * 64];
  __shared__ u16 lV[2][64 * 64];
  __shared__ u16 lP[4][16 * 64];
  const int h = blockIdx.x;
  const int q0 = blockIdx.y * 64;
  const int tid = threadIdx.x;
  const int w = tid >> 6;
  const int l = tid & 63;
  const int sg = ((l & 7) ^ (l >> 3)) * 8;
  const int sr = w * 8 + (l >> 3);

#define FA_STAGE(t_, b_)                                                    \
  do {                                                                      \
    const int kv_ = (t_) * 64;                                              \
    gload_lds16(qkvc + (long)(kv_ + sr) * 1536 + 768 + h * 64 + sg,         \
                lK[b_] + w * 8 * 64);                                       \
    gload_lds16(qkvc + (long)(kv_ + 32 + sr) * 1536 + 768 + h * 64 + sg,    \
                lK[b_] + (32 + w * 8) * 64);                                \
    gload_lds16(vt + (long)(h * 128 + sr) * 1024 + kv_ + sg,                \
                lV[b_] + w * 8 * 64);                                       \
    gload_lds16(vt + (long)(h * 128 + 32 + sr) * 1024 + kv_ + sg,           \
                lV[b_] + (32 + w * 8) * 64);                                \
  } while (0)

  gload_lds16(qkvc + (long)(q0 + sr) * 1536 + h * 64 + sg, lQ + w * 8 * 64);
  gload_lds16(qkvc + (long)(q0 + 32 + sr) * 1536 + h * 64 + sg,
              lQ + (32 + w * 8) * 64);
  FA_STAGE(0, 0);
  __syncthreads();

  const short8 qf0 = frag_read(lQ, w * 16 + (l & 15), 0, l);
  const short8 qf1 = frag_read(lQ, w * 16 + (l & 15), 1, l);

  f32x4 accO[4];
  float m_run[4], l_run[4];
#pragma unroll
  for (int i = 0; i < 4; ++i) {
    accO[i] = (f32x4){0.f, 0.f, 0.f, 0.f};
    m_run[i] = -3.0e38f;
    l_run[i] = 0.f;
  }

  int buf = 0;
  for (int t = 0; t < 16; ++t) {
    if (t + 1 < 16) FA_STAGE(t + 1, buf ^ 1);
    f32x4 s[4];
#pragma unroll
    for (int ni = 0; ni < 4; ++ni) {
      const short8 kf0 = frag_read(lK[buf], ni * 16 + (l & 15), 0, l);
      const short8 kf1 = frag_read(lK[buf], ni * 16 + (l & 15), 1, l);
      s[ni] = MFMA16x16(qf0, kf0, ((f32x4){0.f, 0.f, 0.f, 0.f}));
      s[ni] = MFMA16x16(qf1, kf1, s[ni]);
    }
#pragma unroll
    for (int j = 0; j < 4; ++j) {
      float mx = fmaxf(fmaxf(s[0][j], s[1][j]), fmaxf(s[2][j], s[3][j]));
      mx = fmaxf(mx, __shfl_xor(mx, 1));
      mx = fmaxf(mx, __shfl_xor(mx, 2));
      mx = fmaxf(mx, __shfl_xor(mx, 4));
      mx = fmaxf(mx, __shfl_xor(mx, 8));
      const float mn = fmaxf(m_run[j], mx);
      const float corr = __expf(m_run[j] - mn);
      m_run[j] = mn;
      float ps = 0.f;
#pragma unroll
      for (int ni = 0; ni < 4; ++ni) {
        const float p = __expf(s[ni][j] - mn);
        s[ni][j] = p;
        ps += p;
      }
      ps += __shfl_xor(ps, 1);
      ps += __shfl_xor(ps, 2);
      ps += __shfl_xor(ps, 4);
      ps += __shfl_xor(ps, 8);
      l_run[j] = l_run[j] * corr + ps;
#pragma unroll
      for (int ne = 0; ne < 4; ++ne) accO[ne][j] *= corr;
    }
#pragma unroll
    for (int ni = 0; ni < 4; ++ni) {
#pragma unroll
      for (int j = 0; j < 4; ++j) {
        const int row = (l >> 4) * 4 + j;
        const int col = ni * 16 + (l & 15);
        const int boff = row * 128 + (((col >> 3) ^ (row & 7)) << 4) +
                         (col & 7) * 2;
        *(u16*)((char*)lP[w] + boff) = f2bf(s[ni][j]);
      }
    }
    asm volatile("s_waitcnt lgkmcnt(0)" ::: "memory");
    __builtin_amdgcn_sched_barrier(0);
    const short8 pf0 = frag_read(lP[w], (l & 15), 0, l);
    const short8 pf1 = frag_read(lP[w], (l & 15), 1, l);
#pragma unroll
    for (int ne = 0; ne < 4; ++ne) {
      const short8 vf0 = frag_read(lV[buf], ne * 16 + (l & 15), 0, l);
      const short8 vf1 = frag_read(lV[buf], ne * 16 + (l & 15), 1, l);
      accO[ne] = MFMA16x16(pf0, vf0, accO[ne]);
      accO[ne] = MFMA16x16(pf1, vf1, accO[ne]);
    }
    __syncthreads();
    buf ^= 1;
  }
#undef FA_STAGE

#pragma unroll
  for (int j = 0; j < 4; ++j) {
    const float inv = 1.0f / l_run[j];
    const int row = q0 + w * 16 + (l >> 4) * 4 + j;
#pragma unroll
    for (int ne = 0; ne < 4; ++ne) {
      const int e = ne * 16 + (l & 15);
      if (e < 42)
        cat[(long)row * 512 + h * 42 + e] = f2bf(accO[ne][j] * inv);
    }
  }
}

// ---------------------------------------------------------------------------
// fused prep (coalesced, r11): weight re-layouts + zero(cat pad) + LN1.
// ---------------------------------------------------------------------------
__device__ __forceinline__ void transpose_body(const float* __restrict__ in,
                                               u16* __restrict__ out, int N,
                                               int Kin, int Kpad, int blk,
                                               int gx, int t, float* smem) {
  const int n0 = (blk % gx) * 64;
  const int k0 = (blk / gx) * 64;
  const int tc = t & 63;
  const int tr = t >> 6;
#pragma unroll
  for (int r = 0; r < 16; ++r) {
    const int kr = tr * 16 + r;
    const int kg = k0 + kr;
    smem[kr * 65 + tc] = (kg < Kin) ? in[(long)kg * N + n0 + tc] : 0.f;
  }
  __syncthreads();
  const int nr0 = t >> 4;
  const int kc = (t & 15) * 4;
#pragma unroll
  for (int p = 0; p < 4; ++p) {
    const int nr = nr0 + p * 16;
    ushort4 v;
    v.x = f2bf(smem[(kc + 0) * 65 + nr]);
    v.y = f2bf(smem[(kc + 1) * 65 + nr]);
    v.z = f2bf(smem[(kc + 2) * 65 + nr]);
    v.w = f2bf(smem[(kc + 3) * 65 + nr]);
    *(ushort4*)&out[(long)(n0 + nr) * Kpad + k0 + kc] = v;
  }
}

__global__ void prep_fused(const float* __restrict__ wq,
                           const float* __restrict__ wk,
                           const float* __restrict__ wv,
                           const float* __restrict__ w_proj,
                           const float* __restrict__ w1,
                           const float* __restrict__ w2,
                           const float* __restrict__ x,
                           const float* __restrict__ gamma,
                           const float* __restrict__ beta,
                           u16* __restrict__ BtQKV, u16* __restrict__ wvT,
                           u16* __restrict__ BtP, u16* __restrict__ Bt1,
                           u16* __restrict__ Bt2, u16* __restrict__ cat,
                           u16* __restrict__ n1, float scale) {
  __shared__ float smem[64 * 65];
  const int blk = blockIdx.x;
  const int t = threadIdx.x;
  if (blk < 192) {
    const int pq = blk / 96;
    const int rem = blk % 96;
    const int h = rem >> 3;
    const int d0 = (rem & 7) * 64;
    const float* src = (pq ? wk : wq) + ((long)h * 512 + d0) * 42;
    for (int i = t; i < 2688; i += 256) smem[(i / 42) * 43 + (i % 42)] = src[i];
    __syncthreads();
    const float sc = pq ? 1.0f : scale;
    const int d = t & 63;
#pragma unroll
    for (int p = 0; p < 16; ++p) {
      const int e = (t >> 6) + p * 4;
      const float v = (e < 42) ? smem[d * 43 + e] * sc : 0.f;
      BtQKV[((long)(pq * 768 + h * 64 + e)) * 512 + d0 + d] = f2bf(v);
    }
  } else if (blk < 288) {
    const int b = blk - 192;
    const int h = b >> 3;
    const int d0 = (b & 7) * 64;
    const float* src = wv + ((long)h * 512 + d0) * 42;
    for (int i = t; i < 2688; i += 256) smem[(i / 42) * 43 + (i % 42)] = src[i];
    __syncthreads();
    const int d = t & 63;
#pragma unroll
    for (int p = 0; p < 32; ++p) {
      const int e = (t >> 6) + p * 4;
      const float v = (e < 42) ? smem[d * 43 + e] : 0.f;
      wvT[((long)(h * 128 + e)) * 512 + d0 + d] = f2bf(v);
    }
  } else if (blk < 352) {
    transpose_body(w_proj, BtP, 512, 504, 512, blk - 288, 8, t, smem);
  } else if (blk < 608) {
    transpose_body(w1, Bt1, 2048, 512, 512, blk - 352, 32, t, smem);
  } else if (blk < 864) {
    transpose_body(w2, Bt2, 512, 2048, 2048, blk - 608, 8, t, smem);
  } else if (blk < 896) {
    const int i = (blk - 864) * 256 + t;
    cat[(long)(i >> 3) * 512 + 504 + (i & 7)] = 0;
  } else {
    const int s = blk - 896;
    const float* row = x + (long)s * 512;
    const float v0 = row[t];
    const float v1 = row[t + 256];
    float sum = wred_sum(v0 + v1);
    float sq = wred_sum(v0 * v0 + v1 * v1);
    if ((t & 63) == 0) { smem[t >> 6] = sum; smem[8 + (t >> 6)] = sq; }
    __syncthreads();
    sum = smem[0] + smem[1] + smem[2] + smem[3];
    sq = smem[8] + smem[9] + smem[10] + smem[11];
    const float mu = sum * (1.0f / 512.0f);
    const float rstd = rsqrtf(sq * (1.0f / 512.0f) - mu * mu + 1e-5f);
    n1[(long)s * 512 + t] = f2bf((v0 - mu) * rstd * gamma[t] + beta[t]);
    n1[(long)s * 512 + t + 256] =
        f2bf((v1 - mu) * rstd * gamma[t + 256] + beta[t + 256]);
  }
}

__global__ void ln2_kernel(const float* __restrict__ x,
                           const float* __restrict__ aproj,
                           const float* __restrict__ gamma,
                           const float* __restrict__ beta,
                           const float* __restrict__ b2,
                           u16* __restrict__ n2, float* __restrict__ outp) {
  __shared__ float red[16];
  const int r = blockIdx.x;
  const int t = threadIdx.x;
  const int s = r & 1023;
  const float* xr = x + (long)r * 512;
  const float* ar = aproj + (long)s * 512;
  const float v0 = xr[t] + ar[t];
  const float v1 = xr[t + 256] + ar[t + 256];
  outp[(long)r * 512 + t] = v0 + b2[t];
  outp[(long)r * 512 + t + 256] = v1 + b2[t + 256];
  float sum = wred_sum(v0 + v1);
  float sq = wred_sum(v0 * v0 + v1 * v1);
  if ((t & 63) == 0) { red[t >> 6] = sum; red[8 + (t >> 6)] = sq; }
  __syncthreads();
  sum = red[0] + red[1] + red[2] + red[3];
  sq = red[8] + red[9] + red[10] + red[11];
  const float mu = sum * (1.0f / 512.0f);
  const float rstd = rsqrtf(sq * (1.0f / 512.0f) - mu * mu + 1e-5f);
  n2[(long)r * 512 + t] = f2bf((v0 - mu) * rstd * gamma[t] + beta[t]);
  n2[(long)r * 512 + t + 256] =
      f2bf((v1 - mu) * rstd * gamma[t + 256] + beta[t + 256]);
}

// ---------------------------------------------------------------------------
extern "C" void kernel_launch(void* const* d_in, const int* in_sizes, int n_in,
                              void* d_out, int out_size, void* d_ws,
                              size_t ws_size, hipStream_t stream) {
  const float* x = (const float*)d_in[0];
  const float* wk = (const float*)d_in[1];   // wk before wq in dict order
  const float* wq = (const float*)d_in[2];
  const float* wv = (const float*)d_in[3];
  const float* w_proj = (const float*)d_in[4];
  const float* b_proj = (const float*)d_in[5];
  const float* gamma = (const float*)d_in[6];
  const float* beta = (const float*)d_in[7];
  const float* w1 = (const float*)d_in[8];
  const float* b1 = (const float*)d_in[9];
  const float* w2 = (const float*)d_in[10];
  const float* b2 = (const float*)d_in[11];

  char* base = (char*)d_ws;
  size_t off = 0;
  auto alloc = [&](size_t bytes) -> void* {
    void* p = base + off;
    off += (bytes + 255) & ~(size_t)255;
    return p;
  };
  u16* n1 = (u16*)alloc(1024L * 512 * 2);
  u16* qkvc = (u16*)alloc(1024L * 1536 * 2);
  u16* wvT = (u16*)alloc(1536L * 512 * 2);
  u16* vt = (u16*)alloc(1536L * 1024 * 2);
  u16* cat = (u16*)alloc(1024L * 512 * 2);
  float* aproj = (float*)alloc(1024L * 512 * 4);
  u16* n2 = (u16*)alloc(8192L * 512 * 2);
  u16* hbuf = (u16*)alloc(8192L * 2048 * 2);
  u16* BtQKV = (u16*)alloc(1536L * 512 * 2);
  u16* BtP = (u16*)alloc(512L * 512 * 2);
  u16* Bt1 = (u16*)alloc(2048L * 512 * 2);
  u16* Bt2 = (u16*)alloc(512L * 2048 * 2);
  (void)ws_size; (void)in_sizes; (void)n_in; (void)out_size;

  const float scale = 0.15430334996209191f;  // 42^-0.5 folded into q weights

  prep_fused<<<1920, 256, 0, stream>>>(wq, wk, wv, w_proj, w1, w2, x, gamma,
                                       beta, BtQKV, wvT, BtP, Bt1, Bt2, cat,
                                       n1, scale);
  qkvt_kernel<<<192, 256, 0, stream>>>(n1, BtQKV, qkvc, wvT, vt);
  flash_attn<<<dim3(12, 16), 256, 0, stream>>>(qkvc, vt, cat);
  gemm_k<EP_F32B><<<dim3(8, 4, 1), 256, 0, stream>>>(
      cat, 512, 0, BtP, 512, 0, aproj, 512, 512, b_proj);
  ln2_kernel<<<8192, 256, 0, stream>>>(x, aproj, gamma, beta, b2, n2,
                                       (float*)d_out);
  // h = gelu(n2 @ w1 + b1): NEW 256^2 8-phase kernel (256 blocks, 1/CU)
  gemm8<EP_GELU><<<dim3(32, 8), 512, 0, stream>>>(
      n2, 512, Bt1, 512, hbuf, 2048, 512, b1);
  // MLP2 split-K=2 (r8-proven optimum): atomicAdd into pre-filled d_out
  gemm_k<EP_ATOM><<<dim3(64, 4, 2), 256, 0, stream>>>(
      hbuf, 2048, 1024, Bt2, 2048, 1024, d_out, 512, 1024, nullptr);
}